// Round 4
// baseline (1162.707 us; speedup 1.0000x reference)
//
#include <hip/hip_runtime.h>
#include <math.h>

typedef __attribute__((ext_vector_type(8))) short bf16x8;
typedef __attribute__((ext_vector_type(4))) float f32x4;

#define GLOAD_LDS16(g, l) \
  __builtin_amdgcn_global_load_lds((const __attribute__((address_space(1))) void*)(g), \
                                   (__attribute__((address_space(3))) void*)(l), 16, 0, 0)

__device__ __forceinline__ unsigned short f2b(float f){
  union { float f; unsigned int u; } v; v.f = f;
  unsigned int r = v.u + 0x7fffu + ((v.u >> 16) & 1u);
  return (unsigned short)(r >> 16);
}

// ---------------- transpose + cast: fp32 in[K][N] -> bf16 out[N][K] ----------------
__global__ __launch_bounds__(256) void tcast_kernel(const float* __restrict__ in,
                                                    unsigned short* __restrict__ out,
                                                    int K, int N){
  __shared__ unsigned short tile[32][33];
  int n0 = blockIdx.x*32, k0 = blockIdx.y*32;
  int tx = threadIdx.x, ty = threadIdx.y;   // (32,8)
  #pragma unroll
  for (int j=0;j<4;j++)
    tile[ty+8*j][tx] = f2b(in[(size_t)(k0+ty+8*j)*N + n0+tx]);
  __syncthreads();
  #pragma unroll
  for (int j=0;j<4;j++)
    out[(size_t)(n0+ty+8*j)*K + k0+tx] = tile[tx][ty+8*j];
}

// ---------------- LayerNorm fp32 [4096][2048] -> bf16 ----------------
__global__ __launch_bounds__(256) void ln_kernel(const float* __restrict__ x,
                                                 const float* __restrict__ g,
                                                 const float* __restrict__ b,
                                                 unsigned short* __restrict__ out){
  int row = blockIdx.x; int t = threadIdx.x;
  int l = t & 63, w = t >> 6;
  const float4* xr = (const float4*)(x + (size_t)row*2048);
  float4 v0 = xr[t];
  float4 v1 = xr[256 + t];
  float s = v0.x+v0.y+v0.z+v0.w + v1.x+v1.y+v1.z+v1.w;
  float q = v0.x*v0.x+v0.y*v0.y+v0.z*v0.z+v0.w*v0.w
          + v1.x*v1.x+v1.y*v1.y+v1.z*v1.z+v1.w*v1.w;
  #pragma unroll
  for (int m=1;m<64;m<<=1){ s += __shfl_xor(s,m); q += __shfl_xor(q,m); }
  __shared__ float ls[4], lq[4];
  if (l==0){ ls[w]=s; lq[w]=q; }
  __syncthreads();
  s = ls[0]+ls[1]+ls[2]+ls[3];
  q = lq[0]+lq[1]+lq[2]+lq[3];
  float mu = s * (1.f/2048.f);
  float var = q * (1.f/2048.f) - mu*mu;
  float rs = rsqrtf(var + 1e-5f);
  const float4* gv4 = (const float4*)g;
  const float4* bv4 = (const float4*)b;
  unsigned short* orow = out + (size_t)row*2048;
  #pragma unroll
  for (int p=0;p<2;p++){
    float4 xv = (p==0)? v0 : v1;
    int idx = p*256 + t;
    float4 gv = gv4[idx], bv = bv4[idx];
    ushort4 o;
    o.x = f2b((xv.x-mu)*rs*gv.x + bv.x);
    o.y = f2b((xv.y-mu)*rs*gv.y + bv.y);
    o.z = f2b((xv.z-mu)*rs*gv.z + bv.z);
    o.w = f2b((xv.w-mu)*rs*gv.w + bv.w);
    ((ushort4*)orow)[idx] = o;
  }
}

// ---------------- GEMM: A bf16[M][K], Bt bf16[N][K], epilogues ----------------
// global_load_lds (width-16) staging into LINEAR LDS (m97 structure).
// EPI 1: qk-scatter  out bf16 [b,h,s,d]
// EPI 2: v-scatter   out bf16 [b,h,d,s]
// EPI 3: exact GELU  out bf16 [M][N]
// EPI 4: residual    outf[M][N] = resid + 0.1*acc (fp32)
template<int EPI>
__global__ __launch_bounds__(256) void gemm_kernel(const unsigned short* __restrict__ A,
                                                   const unsigned short* __restrict__ Bt,
                                                   int M, int N, int K,
                                                   const float* __restrict__ resid,
                                                   float* __restrict__ outf,
                                                   unsigned short* __restrict__ outb){
  __shared__ __attribute__((aligned(16))) unsigned short As[128][64];
  __shared__ __attribute__((aligned(16))) unsigned short Bs[128][64];
  int t = threadIdx.x, l = t & 63, w = t >> 6;
  int wr = w >> 1, wc = w & 1;
  int bm = blockIdx.y, bn = blockIdx.x;
  int lr = l & 15, lg = l >> 4;
  const int srow = l >> 3;          // row within the wave's 8-row LDS chunk
  const int scol = (l & 7) * 8;     // short col within row (16B granule)
  const unsigned short* Ab = A  + (size_t)(bm*128)*K;
  const unsigned short* Bb = Bt + (size_t)(bn*128)*K;
  f32x4 acc[4][4];
  #pragma unroll
  for (int i=0;i<4;i++)
    #pragma unroll
    for (int j=0;j<4;j++) acc[i][j] = (f32x4){0.f,0.f,0.f,0.f};

  for (int kt=0; kt<K; kt+=64){
    __syncthreads();
    // stage A+B tiles: 4 chunks/wave each, wave-uniform LDS base + lane*16 dest
    #pragma unroll
    for (int p=0;p<4;p++){
      int chunk = w*4 + p;               // 0..15, covers rows [chunk*8, chunk*8+8)
      int r = chunk*8 + srow;
      GLOAD_LDS16(Ab + (size_t)r*K + kt + scol, &As[chunk*8][0]);
      GLOAD_LDS16(Bb + (size_t)r*K + kt + scol, &Bs[chunk*8][0]);
    }
    __syncthreads();   // compiler emits vmcnt(0) drain before barrier
    #pragma unroll
    for (int kc=0;kc<2;kc++){
      bf16x8 af[4], bfr[4];
      #pragma unroll
      for (int i=0;i<4;i++) af[i]  = *(const bf16x8*)&As[wr*64 + i*16 + lr][kc*32 + lg*8];
      #pragma unroll
      for (int j=0;j<4;j++) bfr[j] = *(const bf16x8*)&Bs[wc*64 + j*16 + lr][kc*32 + lg*8];
      #pragma unroll
      for (int i=0;i<4;i++)
        #pragma unroll
        for (int j=0;j<4;j++)
          acc[i][j] = __builtin_amdgcn_mfma_f32_16x16x32_bf16(af[i], bfr[j], acc[i][j], 0,0,0);
    }
  }

  #pragma unroll
  for (int i=0;i<4;i++){
    #pragma unroll
    for (int j=0;j<4;j++){
      #pragma unroll
      for (int r=0;r<4;r++){
        int row = bm*128 + wr*64 + i*16 + lg*4 + r;
        int col = bn*128 + wc*64 + j*16 + lr;
        float v = acc[i][j][r];
        if (EPI==1){
          int b_ = row>>11, s_ = row&2047, h_ = col>>7, d_ = col&127;
          outb[((size_t)(b_*16+h_)*2048 + s_)*128 + d_] = f2b(v);
        } else if (EPI==2){
          int b_ = row>>11, s_ = row&2047, h_ = col>>7, d_ = col&127;
          outb[((size_t)(b_*16+h_)*128 + d_)*2048 + s_] = f2b(v);
        } else if (EPI==3){
          float gv = 0.5f*v*(1.f + erff(v*0.70710678118f));
          outb[(size_t)row*N + col] = f2b(gv);
        } else {
          size_t idx = (size_t)row*N + col;
          outf[idx] = resid[idx] + 0.1f*v;
        }
      }
    }
  }
}

// ---------------- flash attention fwd, bf16, no mask ----------------
// Q,K: [BH][2048][128]; Vt: [BH][128][2048]; Ctx: [4096][2048]
__global__ __launch_bounds__(256) void attn_kernel(const unsigned short* __restrict__ Q,
                                                   const unsigned short* __restrict__ Kk,
                                                   const unsigned short* __restrict__ Vt,
                                                   unsigned short* __restrict__ Ctx){
  __shared__ unsigned short Qs[64][136];
  __shared__ unsigned short Ks[64][136];
  __shared__ unsigned short Vs[128][72];
  __shared__ unsigned short Ps[4][16][72];
  int t = threadIdx.x, l = t & 63, w = t >> 6;
  int lr = l & 15, lg = l >> 4, l7 = l & 7;
  int bh = blockIdx.y; int q0 = blockIdx.x*64;
  const unsigned short* qp = Q  + (size_t)bh*2048*128 + (size_t)q0*128;
  const unsigned short* kp = Kk + (size_t)bh*2048*128;
  const unsigned short* vp = Vt + (size_t)bh*128*2048;
  {
    int rr = t>>4, cc = (t&15)*8;
    #pragma unroll
    for (int p=0;p<4;p++)
      *(bf16x8*)&Qs[p*16+rr][cc] = *(const bf16x8*)(qp + (size_t)(p*16+rr)*128 + cc);
  }
  __syncthreads();
  bf16x8 qf[4];
  #pragma unroll
  for (int kc=0;kc<4;kc++) qf[kc] = *(const bf16x8*)&Qs[w*16 + lr][kc*32 + lg*8];

  f32x4 o[8];
  #pragma unroll
  for (int dt=0;dt<8;dt++) o[dt] = (f32x4){0.f,0.f,0.f,0.f};
  float m_run[4] = {-1e30f,-1e30f,-1e30f,-1e30f};
  float l_run[4] = {0.f,0.f,0.f,0.f};
  const float scale = 0.08838834764831845f;

  for (int kv0=0; kv0<2048; kv0+=64){
    __syncthreads();
    {
      int rr = t>>4, cc = (t&15)*8;
      #pragma unroll
      for (int p=0;p<4;p++)
        *(bf16x8*)&Ks[p*16+rr][cc] = *(const bf16x8*)(kp + (size_t)(kv0+p*16+rr)*128 + cc);
      int dr = t>>3, c8 = t&7;
      #pragma unroll
      for (int p=0;p<4;p++){
        int d = p*32 + dr;
        *(bf16x8*)&Vs[d][(c8 ^ (d&7))*8] = *(const bf16x8*)(vp + (size_t)d*2048 + kv0 + c8*8);
      }
    }
    __syncthreads();

    f32x4 sc[4];
    #pragma unroll
    for (int nt=0;nt<4;nt++) sc[nt] = (f32x4){0.f,0.f,0.f,0.f};
    #pragma unroll
    for (int kc=0;kc<4;kc++){
      #pragma unroll
      for (int nt=0;nt<4;nt++){
        bf16x8 kf = *(const bf16x8*)&Ks[nt*16 + lr][kc*32 + lg*8];
        sc[nt] = __builtin_amdgcn_mfma_f32_16x16x32_bf16(qf[kc], kf, sc[nt], 0,0,0);
      }
    }
    float alpha[4];
    #pragma unroll
    for (int r=0;r<4;r++){
      float m0 = fmaxf(fmaxf(sc[0][r], sc[1][r]), fmaxf(sc[2][r], sc[3][r])) * scale;
      #pragma unroll
      for (int m=1;m<16;m<<=1) m0 = fmaxf(m0, __shfl_xor(m0, m));
      float mn = fmaxf(m_run[r], m0);
      alpha[r] = __expf(m_run[r] - mn);
      m_run[r] = mn;
      float rs = 0.f;
      #pragma unroll
      for (int nt=0;nt<4;nt++){
        float pv_ = __expf(sc[nt][r]*scale - mn);
        sc[nt][r] = pv_;
        rs += pv_;
      }
      #pragma unroll
      for (int m=1;m<16;m<<=1) rs += __shfl_xor(rs, m);
      l_run[r] = l_run[r]*alpha[r] + rs;
    }
    #pragma unroll
    for (int dt=0;dt<8;dt++)
      #pragma unroll
      for (int r=0;r<4;r++) o[dt][r] *= alpha[r];
    #pragma unroll
    for (int nt=0;nt<4;nt++)
      #pragma unroll
      for (int r=0;r<4;r++)
        Ps[w][lg*4 + r][nt*16 + lr] = f2b(sc[nt][r]);
    __syncthreads();
    #pragma unroll
    for (int kc2=0;kc2<2;kc2++){
      bf16x8 pf = *(const bf16x8*)&Ps[w][lr][kc2*32 + lg*8];
      #pragma unroll
      for (int dt=0;dt<8;dt++){
        bf16x8 vf = *(const bf16x8*)&Vs[dt*16 + lr][(((kc2*4 + lg) ^ l7)*8)];
        o[dt] = __builtin_amdgcn_mfma_f32_16x16x32_bf16(pf, vf, o[dt], 0,0,0);
      }
    }
  }
  int b_ = bh>>4, h_ = bh&15;
  #pragma unroll
  for (int r=0;r<4;r++){
    float inv = 1.f / l_run[r];
    int qrow = q0 + w*16 + lg*4 + r;
    size_t base = ((size_t)(b_*2048) + qrow)*2048 + h_*128;
    #pragma unroll
    for (int dt=0;dt<8;dt++)
      Ctx[base + dt*16 + lr] = f2b(o[dt][r]*inv);
  }
}

// ---------------- workspace layout (bytes) ----------------
#define OFF_WQT  ((size_t)0)
#define OFF_WKT  ((size_t)8388608)
#define OFF_WVT  ((size_t)16777216)
#define OFF_WOT  ((size_t)25165824)
#define OFF_W1T  ((size_t)33554432)
#define OFF_W2T  ((size_t)67108864)
#define OFF_NBF  ((size_t)100663296)
#define OFF_QB   ((size_t)117440512)
#define OFF_KB   ((size_t)134217728)
#define OFF_VTB  ((size_t)150994944)
#define OFF_CTX  ((size_t)167772160)
#define OFF_H1   OFF_QB   // h1 [4096][8192] bf16 overlaps q/k/vt/ctx (all dead by then)

extern "C" void kernel_launch(void* const* d_in, const int* in_sizes, int n_in,
                              void* d_out, int out_size, void* d_ws, size_t ws_size,
                              hipStream_t stream){
  (void)in_sizes; (void)n_in; (void)out_size; (void)ws_size;
  const float* hs   = (const float*)d_in[0];
  const float* Wq   = (const float*)d_in[1];
  const float* Wk   = (const float*)d_in[2];
  const float* Wv   = (const float*)d_in[3];
  const float* Wo   = (const float*)d_in[4];
  const float* W1   = (const float*)d_in[5];
  const float* W2   = (const float*)d_in[6];
  const float* ln1g = (const float*)d_in[7];
  const float* ln1b = (const float*)d_in[8];
  const float* ln2g = (const float*)d_in[9];
  const float* ln2b = (const float*)d_in[10];
  float* out = (float*)d_out;
  char* ws = (char*)d_ws;
  unsigned short* Wqt = (unsigned short*)(ws + OFF_WQT);
  unsigned short* Wkt = (unsigned short*)(ws + OFF_WKT);
  unsigned short* Wvt = (unsigned short*)(ws + OFF_WVT);
  unsigned short* Wot = (unsigned short*)(ws + OFF_WOT);
  unsigned short* W1t = (unsigned short*)(ws + OFF_W1T);
  unsigned short* W2t = (unsigned short*)(ws + OFF_W2T);
  unsigned short* nbf = (unsigned short*)(ws + OFF_NBF);
  unsigned short* qb  = (unsigned short*)(ws + OFF_QB);
  unsigned short* kb  = (unsigned short*)(ws + OFF_KB);
  unsigned short* vtb = (unsigned short*)(ws + OFF_VTB);
  unsigned short* ctx = (unsigned short*)(ws + OFF_CTX);
  unsigned short* h1  = (unsigned short*)(ws + OFF_H1);

  dim3 tb(32,8);
  tcast_kernel<<<dim3(64,64),  tb, 0, stream>>>(Wq, Wqt, 2048, 2048);
  tcast_kernel<<<dim3(64,64),  tb, 0, stream>>>(Wk, Wkt, 2048, 2048);
  tcast_kernel<<<dim3(64,64),  tb, 0, stream>>>(Wv, Wvt, 2048, 2048);
  tcast_kernel<<<dim3(64,64),  tb, 0, stream>>>(Wo, Wot, 2048, 2048);
  tcast_kernel<<<dim3(256,64), tb, 0, stream>>>(W1, W1t, 2048, 8192);
  tcast_kernel<<<dim3(64,256), tb, 0, stream>>>(W2, W2t, 8192, 2048);

  ln_kernel<<<4096, 256, 0, stream>>>(hs, ln1g, ln1b, nbf);

  gemm_kernel<1><<<dim3(16,32), 256, 0, stream>>>(nbf, Wqt, 4096, 2048, 2048, nullptr, nullptr, qb);
  gemm_kernel<1><<<dim3(16,32), 256, 0, stream>>>(nbf, Wkt, 4096, 2048, 2048, nullptr, nullptr, kb);
  gemm_kernel<2><<<dim3(16,32), 256, 0, stream>>>(nbf, Wvt, 4096, 2048, 2048, nullptr, nullptr, vtb);

  attn_kernel<<<dim3(32,32), 256, 0, stream>>>(qb, kb, vtb, ctx);

  gemm_kernel<4><<<dim3(16,32), 256, 0, stream>>>(ctx, Wot, 4096, 2048, 2048, hs, out, nullptr);

  ln_kernel<<<4096, 256, 0, stream>>>(out, ln2g, ln2b, nbf);

  gemm_kernel<3><<<dim3(64,32), 256, 0, stream>>>(nbf, W1t, 4096, 8192, 2048, nullptr, nullptr, h1);
  gemm_kernel<4><<<dim3(16,32), 256, 0, stream>>>(h1, W2t, 4096, 2048, 8192, out, out, nullptr);
}

// Round 5
// 1004.616 us; speedup vs baseline: 1.1574x; 1.1574x over previous
//
#include <hip/hip_runtime.h>
#include <math.h>

typedef __attribute__((ext_vector_type(8))) short bf16x8;
typedef __attribute__((ext_vector_type(4))) float f32x4;

#define GLOAD_LDS16(g, l) \
  __builtin_amdgcn_global_load_lds((const __attribute__((address_space(1))) void*)(g), \
                                   (__attribute__((address_space(3))) void*)(l), 16, 0, 0)

__device__ __forceinline__ unsigned short f2b(float f){
  union { float f; unsigned int u; } v; v.f = f;
  unsigned int r = v.u + 0x7fffu + ((v.u >> 16) & 1u);
  return (unsigned short)(r >> 16);
}

// ---------------- transpose + cast: fp32 in[K][N] -> bf16 out[N][K] ----------------
__global__ __launch_bounds__(256) void tcast_kernel(const float* __restrict__ in,
                                                    unsigned short* __restrict__ out,
                                                    int K, int N){
  __shared__ unsigned short tile[32][33];
  int n0 = blockIdx.x*32, k0 = blockIdx.y*32;
  int tx = threadIdx.x, ty = threadIdx.y;   // (32,8)
  #pragma unroll
  for (int j=0;j<4;j++)
    tile[ty+8*j][tx] = f2b(in[(size_t)(k0+ty+8*j)*N + n0+tx]);
  __syncthreads();
  #pragma unroll
  for (int j=0;j<4;j++)
    out[(size_t)(n0+ty+8*j)*K + k0+tx] = tile[tx][ty+8*j];
}

// ---------------- LayerNorm fp32 [4096][2048] -> bf16 ----------------
__global__ __launch_bounds__(256) void ln_kernel(const float* __restrict__ x,
                                                 const float* __restrict__ g,
                                                 const float* __restrict__ b,
                                                 unsigned short* __restrict__ out){
  int row = blockIdx.x; int t = threadIdx.x;
  int l = t & 63, w = t >> 6;
  const float4* xr = (const float4*)(x + (size_t)row*2048);
  float4 v0 = xr[t];
  float4 v1 = xr[256 + t];
  float s = v0.x+v0.y+v0.z+v0.w + v1.x+v1.y+v1.z+v1.w;
  float q = v0.x*v0.x+v0.y*v0.y+v0.z*v0.z+v0.w*v0.w
          + v1.x*v1.x+v1.y*v1.y+v1.z*v1.z+v1.w*v1.w;
  #pragma unroll
  for (int m=1;m<64;m<<=1){ s += __shfl_xor(s,m); q += __shfl_xor(q,m); }
  __shared__ float ls[4], lq[4];
  if (l==0){ ls[w]=s; lq[w]=q; }
  __syncthreads();
  s = ls[0]+ls[1]+ls[2]+ls[3];
  q = lq[0]+lq[1]+lq[2]+lq[3];
  float mu = s * (1.f/2048.f);
  float var = q * (1.f/2048.f) - mu*mu;
  float rs = rsqrtf(var + 1e-5f);
  const float4* gv4 = (const float4*)g;
  const float4* bv4 = (const float4*)b;
  unsigned short* orow = out + (size_t)row*2048;
  #pragma unroll
  for (int p=0;p<2;p++){
    float4 xv = (p==0)? v0 : v1;
    int idx = p*256 + t;
    float4 gv = gv4[idx], bv = bv4[idx];
    ushort4 o;
    o.x = f2b((xv.x-mu)*rs*gv.x + bv.x);
    o.y = f2b((xv.y-mu)*rs*gv.y + bv.y);
    o.z = f2b((xv.z-mu)*rs*gv.z + bv.z);
    o.w = f2b((xv.w-mu)*rs*gv.w + bv.w);
    ((ushort4*)orow)[idx] = o;
  }
}

// ---------------- GEMM: A bf16[M][K], Bt bf16[N][K], epilogues ----------------
// global_load_lds (width-16) into LINEAR LDS + both-sides XOR granule swizzle:
//   LDS[row][g] = global[row][g ^ (row&7)]  (source pre-swizzled, read swizzled back)
// EPI 1: qk-scatter  out bf16 [b,h,s,d]
// EPI 2: v-scatter   out bf16 [b,h,d,s]
// EPI 3: exact GELU  out bf16 [M][N]
// EPI 4: residual    outf[M][N] = resid + 0.1*acc (fp32)
template<int EPI>
__global__ __launch_bounds__(256) void gemm_kernel(const unsigned short* __restrict__ A,
                                                   const unsigned short* __restrict__ Bt,
                                                   int M, int N, int K,
                                                   const float* __restrict__ resid,
                                                   float* __restrict__ outf,
                                                   unsigned short* __restrict__ outb){
  __shared__ __attribute__((aligned(16))) unsigned short As[128][64];
  __shared__ __attribute__((aligned(16))) unsigned short Bs[128][64];
  int t = threadIdx.x, l = t & 63, w = t >> 6;
  int wr = w >> 1, wc = w & 1;
  int bm = blockIdx.y, bn = blockIdx.x;
  int lr = l & 15, lg = l >> 4;
  const int srow = l >> 3;                        // row within the wave's 8-row LDS chunk
  const int scol = ((l & 7) ^ (srow & 7)) * 8;    // pre-swizzled source granule (shorts)
  const unsigned short* Ab = A  + (size_t)(bm*128)*K;
  const unsigned short* Bb = Bt + (size_t)(bn*128)*K;
  f32x4 acc[4][4];
  #pragma unroll
  for (int i=0;i<4;i++)
    #pragma unroll
    for (int j=0;j<4;j++) acc[i][j] = (f32x4){0.f,0.f,0.f,0.f};

  for (int kt=0; kt<K; kt+=64){
    __syncthreads();
    // stage A+B tiles: 4 chunks/wave each, wave-uniform LDS base + lane*16 linear dest
    #pragma unroll
    for (int p=0;p<4;p++){
      int chunk = w*4 + p;               // 0..15, covers rows [chunk*8, chunk*8+8)
      int r = chunk*8 + srow;
      GLOAD_LDS16(Ab + (size_t)r*K + kt + scol, &As[chunk*8][0]);
      GLOAD_LDS16(Bb + (size_t)r*K + kt + scol, &Bs[chunk*8][0]);
    }
    __syncthreads();
    #pragma unroll
    for (int kc=0;kc<2;kc++){
      bf16x8 af[4], bfr[4];
      #pragma unroll
      for (int i=0;i<4;i++){
        int row = wr*64 + i*16 + lr;
        af[i]  = *(const bf16x8*)&As[row][((kc*4 + lg) ^ (lr & 7)) * 8];
      }
      #pragma unroll
      for (int j=0;j<4;j++){
        int row = wc*64 + j*16 + lr;
        bfr[j] = *(const bf16x8*)&Bs[row][((kc*4 + lg) ^ (lr & 7)) * 8];
      }
      #pragma unroll
      for (int i=0;i<4;i++)
        #pragma unroll
        for (int j=0;j<4;j++)
          acc[i][j] = __builtin_amdgcn_mfma_f32_16x16x32_bf16(af[i], bfr[j], acc[i][j], 0,0,0);
    }
  }

  #pragma unroll
  for (int i=0;i<4;i++){
    #pragma unroll
    for (int j=0;j<4;j++){
      #pragma unroll
      for (int r=0;r<4;r++){
        int row = bm*128 + wr*64 + i*16 + lg*4 + r;
        int col = bn*128 + wc*64 + j*16 + lr;
        float v = acc[i][j][r];
        if (EPI==1){
          int b_ = row>>11, s_ = row&2047, h_ = col>>7, d_ = col&127;
          outb[((size_t)(b_*16+h_)*2048 + s_)*128 + d_] = f2b(v);
        } else if (EPI==2){
          int b_ = row>>11, s_ = row&2047, h_ = col>>7, d_ = col&127;
          outb[((size_t)(b_*16+h_)*128 + d_)*2048 + s_] = f2b(v);
        } else if (EPI==3){
          float gv = 0.5f*v*(1.f + erff(v*0.70710678118f));
          outb[(size_t)row*N + col] = f2b(gv);
        } else {
          size_t idx = (size_t)row*N + col;
          outf[idx] = resid[idx] + 0.1f*v;
        }
      }
    }
  }
}

// ---------------- flash attention fwd, bf16, no mask ----------------
// Q,K: [BH][2048][128]; Vt: [BH][128][2048]; Ctx: [4096][2048]
__global__ __launch_bounds__(256) void attn_kernel(const unsigned short* __restrict__ Q,
                                                   const unsigned short* __restrict__ Kk,
                                                   const unsigned short* __restrict__ Vt,
                                                   unsigned short* __restrict__ Ctx){
  __shared__ unsigned short Qs[64][136];
  __shared__ unsigned short Ks[64][136];
  __shared__ unsigned short Vs[128][72];
  __shared__ unsigned short Ps[4][16][72];
  int t = threadIdx.x, l = t & 63, w = t >> 6;
  int lr = l & 15, lg = l >> 4, l7 = l & 7;
  int bh = blockIdx.y; int q0 = blockIdx.x*64;
  const unsigned short* qp = Q  + (size_t)bh*2048*128 + (size_t)q0*128;
  const unsigned short* kp = Kk + (size_t)bh*2048*128;
  const unsigned short* vp = Vt + (size_t)bh*128*2048;
  {
    int rr = t>>4, cc = (t&15)*8;
    #pragma unroll
    for (int p=0;p<4;p++)
      *(bf16x8*)&Qs[p*16+rr][cc] = *(const bf16x8*)(qp + (size_t)(p*16+rr)*128 + cc);
  }
  __syncthreads();
  bf16x8 qf[4];
  #pragma unroll
  for (int kc=0;kc<4;kc++) qf[kc] = *(const bf16x8*)&Qs[w*16 + lr][kc*32 + lg*8];

  f32x4 o[8];
  #pragma unroll
  for (int dt=0;dt<8;dt++) o[dt] = (f32x4){0.f,0.f,0.f,0.f};
  float m_run[4] = {-1e30f,-1e30f,-1e30f,-1e30f};
  float l_run[4] = {0.f,0.f,0.f,0.f};
  const float scale = 0.08838834764831845f;

  for (int kv0=0; kv0<2048; kv0+=64){
    __syncthreads();
    {
      int rr = t>>4, cc = (t&15)*8;
      #pragma unroll
      for (int p=0;p<4;p++)
        *(bf16x8*)&Ks[p*16+rr][cc] = *(const bf16x8*)(kp + (size_t)(kv0+p*16+rr)*128 + cc);
      int dr = t>>3, c8 = t&7;
      #pragma unroll
      for (int p=0;p<4;p++){
        int d = p*32 + dr;
        *(bf16x8*)&Vs[d][(c8 ^ (d&7))*8] = *(const bf16x8*)(vp + (size_t)d*2048 + kv0 + c8*8);
      }
    }
    __syncthreads();

    f32x4 sc[4];
    #pragma unroll
    for (int nt=0;nt<4;nt++) sc[nt] = (f32x4){0.f,0.f,0.f,0.f};
    #pragma unroll
    for (int kc=0;kc<4;kc++){
      #pragma unroll
      for (int nt=0;nt<4;nt++){
        bf16x8 kf = *(const bf16x8*)&Ks[nt*16 + lr][kc*32 + lg*8];
        sc[nt] = __builtin_amdgcn_mfma_f32_16x16x32_bf16(qf[kc], kf, sc[nt], 0,0,0);
      }
    }
    float alpha[4];
    #pragma unroll
    for (int r=0;r<4;r++){
      float m0 = fmaxf(fmaxf(sc[0][r], sc[1][r]), fmaxf(sc[2][r], sc[3][r])) * scale;
      #pragma unroll
      for (int m=1;m<16;m<<=1) m0 = fmaxf(m0, __shfl_xor(m0, m));
      float mn = fmaxf(m_run[r], m0);
      alpha[r] = __expf(m_run[r] - mn);
      m_run[r] = mn;
      float rs = 0.f;
      #pragma unroll
      for (int nt=0;nt<4;nt++){
        float pv_ = __expf(sc[nt][r]*scale - mn);
        sc[nt][r] = pv_;
        rs += pv_;
      }
      #pragma unroll
      for (int m=1;m<16;m<<=1) rs += __shfl_xor(rs, m);
      l_run[r] = l_run[r]*alpha[r] + rs;
    }
    #pragma unroll
    for (int dt=0;dt<8;dt++)
      #pragma unroll
      for (int r=0;r<4;r++) o[dt][r] *= alpha[r];
    #pragma unroll
    for (int nt=0;nt<4;nt++)
      #pragma unroll
      for (int r=0;r<4;r++)
        Ps[w][lg*4 + r][nt*16 + lr] = f2b(sc[nt][r]);
    __syncthreads();
    #pragma unroll
    for (int kc2=0;kc2<2;kc2++){
      bf16x8 pf = *(const bf16x8*)&Ps[w][lr][kc2*32 + lg*8];
      #pragma unroll
      for (int dt=0;dt<8;dt++){
        bf16x8 vf = *(const bf16x8*)&Vs[dt*16 + lr][(((kc2*4 + lg) ^ l7)*8)];
        o[dt] = __builtin_amdgcn_mfma_f32_16x16x32_bf16(pf, vf, o[dt], 0,0,0);
      }
    }
  }
  int b_ = bh>>4, h_ = bh&15;
  #pragma unroll
  for (int r=0;r<4;r++){
    float inv = 1.f / l_run[r];
    int qrow = q0 + w*16 + lg*4 + r;
    size_t base = ((size_t)(b_*2048) + qrow)*2048 + h_*128;
    #pragma unroll
    for (int dt=0;dt<8;dt++)
      Ctx[base + dt*16 + lr] = f2b(o[dt][r]*inv);
  }
}

// ---------------- workspace layout (bytes) ----------------
#define OFF_WQT  ((size_t)0)
#define OFF_WKT  ((size_t)8388608)
#define OFF_WVT  ((size_t)16777216)
#define OFF_WOT  ((size_t)25165824)
#define OFF_W1T  ((size_t)33554432)
#define OFF_W2T  ((size_t)67108864)
#define OFF_NBF  ((size_t)100663296)
#define OFF_QB   ((size_t)117440512)
#define OFF_KB   ((size_t)134217728)
#define OFF_VTB  ((size_t)150994944)
#define OFF_CTX  ((size_t)167772160)
#define OFF_H1   OFF_QB   // h1 [4096][8192] bf16 overlaps q/k/vt/ctx (all dead by then)

extern "C" void kernel_launch(void* const* d_in, const int* in_sizes, int n_in,
                              void* d_out, int out_size, void* d_ws, size_t ws_size,
                              hipStream_t stream){
  (void)in_sizes; (void)n_in; (void)out_size; (void)ws_size;
  const float* hs   = (const float*)d_in[0];
  const float* Wq   = (const float*)d_in[1];
  const float* Wk   = (const float*)d_in[2];
  const float* Wv   = (const float*)d_in[3];
  const float* Wo   = (const float*)d_in[4];
  const float* W1   = (const float*)d_in[5];
  const float* W2   = (const float*)d_in[6];
  const float* ln1g = (const float*)d_in[7];
  const float* ln1b = (const float*)d_in[8];
  const float* ln2g = (const float*)d_in[9];
  const float* ln2b = (const float*)d_in[10];
  float* out = (float*)d_out;
  char* ws = (char*)d_ws;
  unsigned short* Wqt = (unsigned short*)(ws + OFF_WQT);
  unsigned short* Wkt = (unsigned short*)(ws + OFF_WKT);
  unsigned short* Wvt = (unsigned short*)(ws + OFF_WVT);
  unsigned short* Wot = (unsigned short*)(ws + OFF_WOT);
  unsigned short* W1t = (unsigned short*)(ws + OFF_W1T);
  unsigned short* W2t = (unsigned short*)(ws + OFF_W2T);
  unsigned short* nbf = (unsigned short*)(ws + OFF_NBF);
  unsigned short* qb  = (unsigned short*)(ws + OFF_QB);
  unsigned short* kb  = (unsigned short*)(ws + OFF_KB);
  unsigned short* vtb = (unsigned short*)(ws + OFF_VTB);
  unsigned short* ctx = (unsigned short*)(ws + OFF_CTX);
  unsigned short* h1  = (unsigned short*)(ws + OFF_H1);

  dim3 tb(32,8);
  tcast_kernel<<<dim3(64,64),  tb, 0, stream>>>(Wq, Wqt, 2048, 2048);
  tcast_kernel<<<dim3(64,64),  tb, 0, stream>>>(Wk, Wkt, 2048, 2048);
  tcast_kernel<<<dim3(64,64),  tb, 0, stream>>>(Wv, Wvt, 2048, 2048);
  tcast_kernel<<<dim3(64,64),  tb, 0, stream>>>(Wo, Wot, 2048, 2048);
  tcast_kernel<<<dim3(256,64), tb, 0, stream>>>(W1, W1t, 2048, 8192);
  tcast_kernel<<<dim3(64,256), tb, 0, stream>>>(W2, W2t, 8192, 2048);

  ln_kernel<<<4096, 256, 0, stream>>>(hs, ln1g, ln1b, nbf);

  gemm_kernel<1><<<dim3(16,32), 256, 0, stream>>>(nbf, Wqt, 4096, 2048, 2048, nullptr, nullptr, qb);
  gemm_kernel<1><<<dim3(16,32), 256, 0, stream>>>(nbf, Wkt, 4096, 2048, 2048, nullptr, nullptr, kb);
  gemm_kernel<2><<<dim3(16,32), 256, 0, stream>>>(nbf, Wvt, 4096, 2048, 2048, nullptr, nullptr, vtb);

  attn_kernel<<<dim3(32,32), 256, 0, stream>>>(qb, kb, vtb, ctx);

  gemm_kernel<4><<<dim3(16,32), 256, 0, stream>>>(ctx, Wot, 4096, 2048, 2048, hs, out, nullptr);

  ln_kernel<<<4096, 256, 0, stream>>>(out, ln2g, ln2b, nbf);

  gemm_kernel<3><<<dim3(64,32), 256, 0, stream>>>(nbf, W1t, 4096, 8192, 2048, nullptr, nullptr, h1);
  gemm_kernel<4><<<dim3(16,32), 256, 0, stream>>>(h1, W2t, 4096, 2048, 8192, out, out, nullptr);
}